// Round 15
// baseline (40.074 us; speedup 1.0000x reference)
//
#include <hip/hip_runtime.h>
#include <stdint.h>

// AeTransformer_44839458570443: 3-NN inverse-distance interpolation + (tanh+1)/2.
// xyz1: [B,3,N] fp32, xyz2: [B,3,S] fp32, points2: [B,1,S] fp32 -> out [B,N] fp32.
//
// Selection bit-matches the reference fp32 expanded distance
//   d = (-2*((x*x'+y*y')+z*z') + ||q||^2) + ||p||^2   (fp32, no FMA)
// ordered by (d, index).
//
// Round 15: Q=4 x SPLIT-4. Each lane owns 4 query slots; each of the block's
// 4 waves scans 16 of 64 groups for all 4 slots. Per-CU LDS broadcast traffic
// = 2048 ds_read_b128 (~10us); per-wave VALU ~2.6k inst (~9us at 4 waves/
// SIMD); wave count 4096 = 4/SIMD (R14-proven). VGPR ~100 under the 128 cap
// of __launch_bounds__(256,4) (R8: Q=4 state measured 80 VGPR -> no spill).
// MERGE: wave w owns query-slot w; INS5-merges 3 partners' 5-key lists via
// 20KB LDS exchange (disjoint group halves + unique gid bits -> merged min-5
// == full-scan min-5, semantics identical to R12-R14).
// PHASE A (proxy): per group of 8, 3-FMA distances + min tree -> group min;
//   keep 5 best (group-min | gid) keys per slot. Lemma: at most 3 groups can
//   have min <= d3; 5 kept for proxy margin.
// PHASE C (global/L1 divergent gathers; R8-R14-proven, 0 bank conflicts):
//   FMA-proxy rescan of 40 survivors, 9-bit-quantized 6-slot screen,
//   exact replicated ref_d on 6, (d,idx) sort, replicated fp32 weight chain.
static constexpr int B = 4;
static constexpr int N = 65536;
static constexpr int S = 512;

__global__ __launch_bounds__(256) void prep_kernel(const float* __restrict__ xyz2,
                                                   float4* __restrict__ ws) {
    int t = blockIdx.x * 256 + threadIdx.x;
    if (t >= B * S) return;
    int b = t >> 9, s = t & 511;
    const float* p = xyz2 + (size_t)b * 3 * S;
    float x = p[s], y = p[s + S], z = p[s + 2 * S];
    float c = __fadd_rn(__fadd_rn(__fmul_rn(x, x), __fmul_rn(y, y)), __fmul_rn(z, z));
    ws[t] = make_float4(x, y, z, c);
}

// Reference-replicated fp32 distance (numpy order, no contraction)
__device__ __forceinline__ float ref_d(float x1, float y1, float z1, float ssrc, float4 p) {
    float dot = __fadd_rn(__fadd_rn(__fmul_rn(x1, p.x), __fmul_rn(y1, p.y)),
                          __fmul_rn(z1, p.z));
    float t = __fmul_rn(dot, -2.0f);
    return __fadd_rn(__fadd_rn(t, ssrc), p.w);
}

#define CAS(da_, ia_, db_, ib_)                                     \
    {                                                               \
        bool sw_ = (db_ < da_) || ((db_ == da_) && (ib_ < ia_));    \
        float tda_ = sw_ ? db_ : da_;                               \
        int tia_ = sw_ ? ib_ : ia_;                                 \
        db_ = sw_ ? da_ : db_;                                      \
        ib_ = sw_ ? ia_ : ib_;                                      \
        da_ = tda_;                                                 \
        ia_ = tia_;                                                 \
    }

// sorted insert into ascending 5-list (named slots)
#define INS5L(A0, A1, A2, A3, A4, k)                                \
    {                                                               \
        float t4 = __builtin_amdgcn_fmed3f(A3, (k), A4);            \
        float t3 = __builtin_amdgcn_fmed3f(A2, (k), A3);            \
        float t2 = __builtin_amdgcn_fmed3f(A1, (k), A2);            \
        float t1 = __builtin_amdgcn_fmed3f(A0, (k), A1);            \
        A0 = fminf(A0, (k));                                        \
        A1 = t1; A2 = t2; A3 = t3; A4 = t4;                         \
    }

#define INS6(k)                                                     \
    {                                                               \
        float t5 = __builtin_amdgcn_fmed3f(m4, (k), m5);            \
        float t4 = __builtin_amdgcn_fmed3f(m3, (k), m4);            \
        float t3 = __builtin_amdgcn_fmed3f(m2, (k), m3);            \
        float t2 = __builtin_amdgcn_fmed3f(m1, (k), m2);            \
        float t1 = __builtin_amdgcn_fmed3f(m0, (k), m1);            \
        m0 = fminf(m0, (k));                                        \
        m1 = t1; m2 = t2; m3 = t3; m4 = t4; m5 = t5;                \
    }

// Phase-A body for one query slot on a group of 8 already in p[]
#define PROC_GQ(NX, NY, NZ, CC, A0, A1, A2, A3, A4, gid)                      \
    {                                                                         \
        float e[8];                                                           \
        _Pragma("unroll") for (int j = 0; j < 8; ++j)                         \
            e[j] = fmaf(NX, p[j].x,                                           \
                        fmaf(NY, p[j].y, fmaf(NZ, p[j].z, p[j].w)));          \
        float mA = fminf(fminf(e[0], e[1]), e[2]);                            \
        float mB = fminf(fminf(e[3], e[4]), e[5]);                            \
        float mC = fminf(fminf(mA, mB), e[6]);                                \
        float gm = fminf(mC, e[7]);                                           \
        float gkey = __uint_as_float(                                         \
            (__float_as_uint(gm + CC) & 0xFFFFFFC0u) | (uint32_t)(gid));      \
        INS5L(A0, A1, A2, A3, A4, gkey);                                      \
    }

// Merge 3 partner 5-lists (rows R..R+4, partner tids P0,P1,P2) into A-list
#define MERGE3(R, A0, A1, A2, A3, A4, P0, P1, P2)                             \
    {                                                                         \
        _Pragma("unroll") for (int j = 0; j < 5; ++j) {                       \
            float k0 = keys_sh[(R) + j][P0];                                  \
            float k1 = keys_sh[(R) + j][P1];                                  \
            float k2 = keys_sh[(R) + j][P2];                                  \
            INS5L(A0, A1, A2, A3, A4, k0);                                    \
            INS5L(A0, A1, A2, A3, A4, k1);                                    \
            INS5L(A0, A1, A2, A3, A4, k2);                                    \
        }                                                                     \
    }

// Phase C + refine + epilogue for one query (all names passed explicitly)
#define PHASE_C(NX, NY, NZ, CC, X1, Y1, Z1, SS, K0, K1, K2, K3, K4, NOUT)     \
    {                                                                         \
        float m0 = 3.0e38f, m1 = 3.0e38f, m2 = 3.0e38f,                       \
              m3 = 3.0e38f, m4 = 3.0e38f, m5 = 3.0e38f;                       \
        float gkeys[5] = {K0, K1, K2, K3, K4};                                \
        _Pragma("unroll") for (int t = 0; t < 5; ++t) {                       \
            int gbase = (int)(__float_as_uint(gkeys[t]) & 63u) << 3;          \
            _Pragma("unroll") for (int j = 0; j < 8; ++j) {                   \
                float4 p = wvec[gbase + j]; /* divergent gather, L1 */        \
                float e2 = fmaf(NX, p.x,                                      \
                                fmaf(NY, p.y, fmaf(NZ, p.z, p.w + CC)));      \
                float k = __uint_as_float((__float_as_uint(e2) & 0xFFFFFE00u) \
                                          | (uint32_t)(gbase + j));           \
                INS6(k);                                                      \
            }                                                                 \
        }                                                                     \
        int gi[6];                                                            \
        float dd[6];                                                          \
        gi[0] = (int)(__float_as_uint(m0) & 511u);                            \
        gi[1] = (int)(__float_as_uint(m1) & 511u);                            \
        gi[2] = (int)(__float_as_uint(m2) & 511u);                            \
        gi[3] = (int)(__float_as_uint(m3) & 511u);                            \
        gi[4] = (int)(__float_as_uint(m4) & 511u);                            \
        gi[5] = (int)(__float_as_uint(m5) & 511u);                            \
        _Pragma("unroll") for (int j = 0; j < 6; ++j)                         \
            dd[j] = ref_d(X1, Y1, Z1, SS, wvec[gi[j]]);                       \
        _Pragma("unroll") for (int pp = 0; pp < 3; ++pp)                      \
            _Pragma("unroll") for (int i = 4; i >= pp; --i)                   \
                CAS(dd[i], gi[i], dd[i + 1], gi[i + 1]);                      \
        const float EPS32 = 1e-8f;                                            \
        float r0 = __fdiv_rn(1.0f, __fadd_rn(dd[0], EPS32));                  \
        float r1 = __fdiv_rn(1.0f, __fadd_rn(dd[1], EPS32));                  \
        float r2 = __fdiv_rn(1.0f, __fadd_rn(dd[2], EPS32));                  \
        float rs = __fadd_rn(__fadd_rn(r0, r1), r2);                          \
        float w0 = __fdiv_rn(r0, rs);                                         \
        float w1 = __fdiv_rn(r1, rs);                                         \
        float w2 = __fdiv_rn(r2, rs);                                         \
        float interp = __fadd_rn(__fadd_rn(__fmul_rn(f[gi[0]], w0),           \
                                           __fmul_rn(f[gi[1]], w1)),          \
                                 __fmul_rn(f[gi[2]], w2));                    \
        float th = tanhf(interp);                                             \
        out[((size_t)b << 16) | (uint32_t)(NOUT)] =                           \
            __fmul_rn(__fadd_rn(th, 1.0f), 0.5f);                             \
    }

__global__ __launch_bounds__(256, 4) void knn3_kernel(const float* __restrict__ xyz1,
                                                      const float* __restrict__ points2,
                                                      const float4* __restrict__ ws,
                                                      float* __restrict__ out) {
    __shared__ float4 tile[S];          // 8 KB candidate table
    __shared__ float keys_sh[20][256];  // 20 KB per-slot key exchange
    const int tid = threadIdx.x;
    const int lane = tid & 63;
    const int wid_u = __builtin_amdgcn_readfirstlane(tid >> 6);  // wave 0-3
    const int b = blockIdx.x >> 8;      // 256 blocks per batch
    const int base = (blockIdx.x & 255) << 8;  // block covers 256 queries

    const float4* __restrict__ wvec = ws + (size_t)b * S;
    tile[tid] = wvec[tid];
    tile[tid + 256] = wvec[tid + 256];
    __syncthreads();

    // 4 query slots per lane: n_s = base + s*64 + lane (coalesced loads)
    const int n_0 = base + lane, n_1 = n_0 + 64, n_2 = n_0 + 128, n_3 = n_0 + 192;
    const float* q = xyz1 + (size_t)b * 3 * N;
    float x_0 = q[n_0], y_0 = q[n_0 + N], z_0 = q[n_0 + 2 * N];
    float x_1 = q[n_1], y_1 = q[n_1 + N], z_1 = q[n_1 + 2 * N];
    float x_2 = q[n_2], y_2 = q[n_2 + N], z_2 = q[n_2 + 2 * N];
    float x_3 = q[n_3], y_3 = q[n_3 + N], z_3 = q[n_3 + 2 * N];
#define MKC(s)                                                                     \
    float ss_##s = __fadd_rn(__fadd_rn(__fmul_rn(x_##s, x_##s),                    \
                                       __fmul_rn(y_##s, y_##s)),                   \
                             __fmul_rn(z_##s, z_##s));                             \
    float c_##s = ss_##s + 0.25f;                                                  \
    float nx_##s = -2.0f * x_##s, ny_##s = -2.0f * y_##s, nz_##s = -2.0f * z_##s;
    MKC(0) MKC(1) MKC(2) MKC(3)
#undef MKC

    // ---- Phase A: scan own 16 groups; 5 best (min|gid) per slot ----
    float A0 = 3.0e38f, A1 = 3.0e38f, A2 = 3.0e38f, A3 = 3.0e38f, A4 = 3.0e38f;
    float B0 = 3.0e38f, B1 = 3.0e38f, B2 = 3.0e38f, B3 = 3.0e38f, B4 = 3.0e38f;
    float C0 = 3.0e38f, C1 = 3.0e38f, C2 = 3.0e38f, C3 = 3.0e38f, C4 = 3.0e38f;
    float D0 = 3.0e38f, D1 = 3.0e38f, D2 = 3.0e38f, D3 = 3.0e38f, D4 = 3.0e38f;
    const int gid0 = wid_u << 4;
#pragma unroll 2
    for (int g = 0; g < 16; ++g) {
        const int gid = gid0 + g;
        float4 p[8];
#pragma unroll
        for (int j = 0; j < 8; ++j) p[j] = tile[gid * 8 + j];  // broadcast b128
        PROC_GQ(nx_0, ny_0, nz_0, c_0, A0, A1, A2, A3, A4, gid);
        PROC_GQ(nx_1, ny_1, nz_1, c_1, B0, B1, B2, B3, B4, gid);
        PROC_GQ(nx_2, ny_2, nz_2, c_2, C0, C1, C2, C3, C4, gid);
        PROC_GQ(nx_3, ny_3, nz_3, c_3, D0, D1, D2, D3, D4, gid);
    }

    // ---- publish all 20 keys ----
    keys_sh[0][tid] = A0; keys_sh[1][tid] = A1; keys_sh[2][tid] = A2;
    keys_sh[3][tid] = A3; keys_sh[4][tid] = A4;
    keys_sh[5][tid] = B0; keys_sh[6][tid] = B1; keys_sh[7][tid] = B2;
    keys_sh[8][tid] = B3; keys_sh[9][tid] = B4;
    keys_sh[10][tid] = C0; keys_sh[11][tid] = C1; keys_sh[12][tid] = C2;
    keys_sh[13][tid] = C3; keys_sh[14][tid] = C4;
    keys_sh[15][tid] = D0; keys_sh[16][tid] = D1; keys_sh[17][tid] = D2;
    keys_sh[18][tid] = D3; keys_sh[19][tid] = D4;
    __syncthreads();

    // ---- merge + phase C: wave w owns query slot w ----
    const float* f = points2 + (size_t)b * S;  // D = 1
    if (wid_u == 0) {
        MERGE3(0, A0, A1, A2, A3, A4, lane + 64, lane + 128, lane + 192);
        PHASE_C(nx_0, ny_0, nz_0, c_0, x_0, y_0, z_0, ss_0,
                A0, A1, A2, A3, A4, n_0);
    } else if (wid_u == 1) {
        MERGE3(5, B0, B1, B2, B3, B4, lane, lane + 128, lane + 192);
        PHASE_C(nx_1, ny_1, nz_1, c_1, x_1, y_1, z_1, ss_1,
                B0, B1, B2, B3, B4, n_1);
    } else if (wid_u == 2) {
        MERGE3(10, C0, C1, C2, C3, C4, lane, lane + 64, lane + 192);
        PHASE_C(nx_2, ny_2, nz_2, c_2, x_2, y_2, z_2, ss_2,
                C0, C1, C2, C3, C4, n_2);
    } else {
        MERGE3(15, D0, D1, D2, D3, D4, lane, lane + 64, lane + 128);
        PHASE_C(nx_3, ny_3, nz_3, c_3, x_3, y_3, z_3, ss_3,
                D0, D1, D2, D3, D4, n_3);
    }
}

extern "C" void kernel_launch(void* const* d_in, const int* in_sizes, int n_in,
                              void* d_out, int out_size, void* d_ws, size_t ws_size,
                              hipStream_t stream) {
    const float* xyz1 = (const float*)d_in[0];
    const float* xyz2 = (const float*)d_in[1];
    const float* points2 = (const float*)d_in[2];
    float* out = (float*)d_out;
    float4* ws = (float4*)d_ws;  // B*S*16 = 32 KB

    prep_kernel<<<(B * S + 255) / 256, 256, 0, stream>>>(xyz2, ws);
    // 1024 blocks x 256 threads: block covers 256 queries (Q=4 per lane),
    // candidates split 4 ways across the block's waves
    knn3_kernel<<<(B * N) / 256, 256, 0, stream>>>(xyz1, points2, ws, out);
}

// Round 16
// 34.844 us; speedup vs baseline: 1.1501x; 1.1501x over previous
//
#include <hip/hip_runtime.h>
#include <stdint.h>

// AeTransformer_44839458570443: 3-NN inverse-distance interpolation + (tanh+1)/2.
// xyz1: [B,3,N] fp32, xyz2: [B,3,S] fp32, points2: [B,1,S] fp32 -> out [B,N] fp32.
//
// Selection bit-matches the reference fp32 expanded distance
//   d = (-2*((x*x'+y*y')+z*z') + ||q||^2) + ||p||^2   (fp32, no FMA)
// ordered by (d, index).
//
// Round 16 = Round 15 with ONE change: phase C + refine gathers read the LDS
// tile instead of global. R15's budget: phase-A VALU ~16us (2.15x-derated),
// LDS-A ~10us, residual ~15us attributed to phase C's 40 fully-divergent
// global dwordx4 gathers/lane (64 distinct addresses per wave-instr serialize
// in TA/L1). LDS random b128 gathers in 8KB cost ~12-20cyc each on the
// lightly-loaded LDS pipe (~4-6us total). A/B vs R15 isolates phase C.
// PHASE A (proxy): Q=4 x split-4; per group of 8, 3-FMA distances + min tree
//   -> group min; keep 5 best (group-min | gid) keys per slot. Lemma: at most
//   3 groups can have min <= d3; 5 kept for proxy margin.
// MERGE: wave w owns query-slot w; INS5-merges 3 partners' lists via LDS.
// PHASE C (LDS divergent gathers): FMA-proxy rescan of 40 survivors,
//   9-bit-quantized 6-slot screen, exact replicated ref_d on 6, (d,idx) sort,
//   replicated fp32 weight chain (proven R2-R15).
static constexpr int B = 4;
static constexpr int N = 65536;
static constexpr int S = 512;

__global__ __launch_bounds__(256) void prep_kernel(const float* __restrict__ xyz2,
                                                   float4* __restrict__ ws) {
    int t = blockIdx.x * 256 + threadIdx.x;
    if (t >= B * S) return;
    int b = t >> 9, s = t & 511;
    const float* p = xyz2 + (size_t)b * 3 * S;
    float x = p[s], y = p[s + S], z = p[s + 2 * S];
    float c = __fadd_rn(__fadd_rn(__fmul_rn(x, x), __fmul_rn(y, y)), __fmul_rn(z, z));
    ws[t] = make_float4(x, y, z, c);
}

// Reference-replicated fp32 distance (numpy order, no contraction)
__device__ __forceinline__ float ref_d(float x1, float y1, float z1, float ssrc, float4 p) {
    float dot = __fadd_rn(__fadd_rn(__fmul_rn(x1, p.x), __fmul_rn(y1, p.y)),
                          __fmul_rn(z1, p.z));
    float t = __fmul_rn(dot, -2.0f);
    return __fadd_rn(__fadd_rn(t, ssrc), p.w);
}

#define CAS(da_, ia_, db_, ib_)                                     \
    {                                                               \
        bool sw_ = (db_ < da_) || ((db_ == da_) && (ib_ < ia_));    \
        float tda_ = sw_ ? db_ : da_;                               \
        int tia_ = sw_ ? ib_ : ia_;                                 \
        db_ = sw_ ? da_ : db_;                                      \
        ib_ = sw_ ? ia_ : ib_;                                      \
        da_ = tda_;                                                 \
        ia_ = tia_;                                                 \
    }

// sorted insert into ascending 5-list (named slots)
#define INS5L(A0, A1, A2, A3, A4, k)                                \
    {                                                               \
        float t4 = __builtin_amdgcn_fmed3f(A3, (k), A4);            \
        float t3 = __builtin_amdgcn_fmed3f(A2, (k), A3);            \
        float t2 = __builtin_amdgcn_fmed3f(A1, (k), A2);            \
        float t1 = __builtin_amdgcn_fmed3f(A0, (k), A1);            \
        A0 = fminf(A0, (k));                                        \
        A1 = t1; A2 = t2; A3 = t3; A4 = t4;                         \
    }

#define INS6(k)                                                     \
    {                                                               \
        float t5 = __builtin_amdgcn_fmed3f(m4, (k), m5);            \
        float t4 = __builtin_amdgcn_fmed3f(m3, (k), m4);            \
        float t3 = __builtin_amdgcn_fmed3f(m2, (k), m3);            \
        float t2 = __builtin_amdgcn_fmed3f(m1, (k), m2);            \
        float t1 = __builtin_amdgcn_fmed3f(m0, (k), m1);            \
        m0 = fminf(m0, (k));                                        \
        m1 = t1; m2 = t2; m3 = t3; m4 = t4; m5 = t5;                \
    }

// Phase-A body for one query slot on a group of 8 already in p[]
#define PROC_GQ(NX, NY, NZ, CC, A0, A1, A2, A3, A4, gid)                      \
    {                                                                         \
        float e[8];                                                           \
        _Pragma("unroll") for (int j = 0; j < 8; ++j)                         \
            e[j] = fmaf(NX, p[j].x,                                           \
                        fmaf(NY, p[j].y, fmaf(NZ, p[j].z, p[j].w)));          \
        float mA = fminf(fminf(e[0], e[1]), e[2]);                            \
        float mB = fminf(fminf(e[3], e[4]), e[5]);                            \
        float mC = fminf(fminf(mA, mB), e[6]);                                \
        float gm = fminf(mC, e[7]);                                           \
        float gkey = __uint_as_float(                                         \
            (__float_as_uint(gm + CC) & 0xFFFFFFC0u) | (uint32_t)(gid));      \
        INS5L(A0, A1, A2, A3, A4, gkey);                                      \
    }

// Merge 3 partner 5-lists (rows R..R+4, partner tids P0,P1,P2) into A-list
#define MERGE3(R, A0, A1, A2, A3, A4, P0, P1, P2)                             \
    {                                                                         \
        _Pragma("unroll") for (int j = 0; j < 5; ++j) {                       \
            float k0 = keys_sh[(R) + j][P0];                                  \
            float k1 = keys_sh[(R) + j][P1];                                  \
            float k2 = keys_sh[(R) + j][P2];                                  \
            INS5L(A0, A1, A2, A3, A4, k0);                                    \
            INS5L(A0, A1, A2, A3, A4, k1);                                    \
            INS5L(A0, A1, A2, A3, A4, k2);                                    \
        }                                                                     \
    }

// Phase C + refine + epilogue for one query — ALL gathers from LDS tile
#define PHASE_C(NX, NY, NZ, CC, X1, Y1, Z1, SS, K0, K1, K2, K3, K4, NOUT)     \
    {                                                                         \
        float m0 = 3.0e38f, m1 = 3.0e38f, m2 = 3.0e38f,                       \
              m3 = 3.0e38f, m4 = 3.0e38f, m5 = 3.0e38f;                       \
        float gkeys[5] = {K0, K1, K2, K3, K4};                                \
        _Pragma("unroll") for (int t = 0; t < 5; ++t) {                       \
            int gbase = (int)(__float_as_uint(gkeys[t]) & 63u) << 3;          \
            _Pragma("unroll") for (int j = 0; j < 8; ++j) {                   \
                float4 p = tile[gbase + j]; /* divergent LDS gather */        \
                float e2 = fmaf(NX, p.x,                                      \
                                fmaf(NY, p.y, fmaf(NZ, p.z, p.w + CC)));      \
                float k = __uint_as_float((__float_as_uint(e2) & 0xFFFFFE00u) \
                                          | (uint32_t)(gbase + j));           \
                INS6(k);                                                      \
            }                                                                 \
        }                                                                     \
        int gi[6];                                                            \
        float dd[6];                                                          \
        gi[0] = (int)(__float_as_uint(m0) & 511u);                            \
        gi[1] = (int)(__float_as_uint(m1) & 511u);                            \
        gi[2] = (int)(__float_as_uint(m2) & 511u);                            \
        gi[3] = (int)(__float_as_uint(m3) & 511u);                            \
        gi[4] = (int)(__float_as_uint(m4) & 511u);                            \
        gi[5] = (int)(__float_as_uint(m5) & 511u);                            \
        _Pragma("unroll") for (int j = 0; j < 6; ++j)                         \
            dd[j] = ref_d(X1, Y1, Z1, SS, tile[gi[j]]);                       \
        _Pragma("unroll") for (int pp = 0; pp < 3; ++pp)                      \
            _Pragma("unroll") for (int i = 4; i >= pp; --i)                   \
                CAS(dd[i], gi[i], dd[i + 1], gi[i + 1]);                      \
        const float EPS32 = 1e-8f;                                            \
        float r0 = __fdiv_rn(1.0f, __fadd_rn(dd[0], EPS32));                  \
        float r1 = __fdiv_rn(1.0f, __fadd_rn(dd[1], EPS32));                  \
        float r2 = __fdiv_rn(1.0f, __fadd_rn(dd[2], EPS32));                  \
        float rs = __fadd_rn(__fadd_rn(r0, r1), r2);                          \
        float w0 = __fdiv_rn(r0, rs);                                         \
        float w1 = __fdiv_rn(r1, rs);                                         \
        float w2 = __fdiv_rn(r2, rs);                                         \
        float interp = __fadd_rn(__fadd_rn(__fmul_rn(f[gi[0]], w0),           \
                                           __fmul_rn(f[gi[1]], w1)),          \
                                 __fmul_rn(f[gi[2]], w2));                    \
        float th = tanhf(interp);                                             \
        out[((size_t)b << 16) | (uint32_t)(NOUT)] =                           \
            __fmul_rn(__fadd_rn(th, 1.0f), 0.5f);                             \
    }

__global__ __launch_bounds__(256, 4) void knn3_kernel(const float* __restrict__ xyz1,
                                                      const float* __restrict__ points2,
                                                      const float4* __restrict__ ws,
                                                      float* __restrict__ out) {
    __shared__ float4 tile[S];          // 8 KB candidate table
    __shared__ float keys_sh[20][256];  // 20 KB per-slot key exchange
    const int tid = threadIdx.x;
    const int lane = tid & 63;
    const int wid_u = __builtin_amdgcn_readfirstlane(tid >> 6);  // wave 0-3
    const int b = blockIdx.x >> 8;      // 256 blocks per batch
    const int base = (blockIdx.x & 255) << 8;  // block covers 256 queries

    const float4* __restrict__ wvec = ws + (size_t)b * S;
    tile[tid] = wvec[tid];
    tile[tid + 256] = wvec[tid + 256];
    __syncthreads();

    // 4 query slots per lane: n_s = base + s*64 + lane (coalesced loads)
    const int n_0 = base + lane, n_1 = n_0 + 64, n_2 = n_0 + 128, n_3 = n_0 + 192;
    const float* q = xyz1 + (size_t)b * 3 * N;
    float x_0 = q[n_0], y_0 = q[n_0 + N], z_0 = q[n_0 + 2 * N];
    float x_1 = q[n_1], y_1 = q[n_1 + N], z_1 = q[n_1 + 2 * N];
    float x_2 = q[n_2], y_2 = q[n_2 + N], z_2 = q[n_2 + 2 * N];
    float x_3 = q[n_3], y_3 = q[n_3 + N], z_3 = q[n_3 + 2 * N];
#define MKC(s)                                                                     \
    float ss_##s = __fadd_rn(__fadd_rn(__fmul_rn(x_##s, x_##s),                    \
                                       __fmul_rn(y_##s, y_##s)),                   \
                             __fmul_rn(z_##s, z_##s));                             \
    float c_##s = ss_##s + 0.25f;                                                  \
    float nx_##s = -2.0f * x_##s, ny_##s = -2.0f * y_##s, nz_##s = -2.0f * z_##s;
    MKC(0) MKC(1) MKC(2) MKC(3)
#undef MKC

    // ---- Phase A: scan own 16 groups; 5 best (min|gid) per slot ----
    float A0 = 3.0e38f, A1 = 3.0e38f, A2 = 3.0e38f, A3 = 3.0e38f, A4 = 3.0e38f;
    float B0 = 3.0e38f, B1 = 3.0e38f, B2 = 3.0e38f, B3 = 3.0e38f, B4 = 3.0e38f;
    float C0 = 3.0e38f, C1 = 3.0e38f, C2 = 3.0e38f, C3 = 3.0e38f, C4 = 3.0e38f;
    float D0 = 3.0e38f, D1 = 3.0e38f, D2 = 3.0e38f, D3 = 3.0e38f, D4 = 3.0e38f;
    const int gid0 = wid_u << 4;
#pragma unroll 2
    for (int g = 0; g < 16; ++g) {
        const int gid = gid0 + g;
        float4 p[8];
#pragma unroll
        for (int j = 0; j < 8; ++j) p[j] = tile[gid * 8 + j];  // broadcast b128
        PROC_GQ(nx_0, ny_0, nz_0, c_0, A0, A1, A2, A3, A4, gid);
        PROC_GQ(nx_1, ny_1, nz_1, c_1, B0, B1, B2, B3, B4, gid);
        PROC_GQ(nx_2, ny_2, nz_2, c_2, C0, C1, C2, C3, C4, gid);
        PROC_GQ(nx_3, ny_3, nz_3, c_3, D0, D1, D2, D3, D4, gid);
    }

    // ---- publish all 20 keys ----
    keys_sh[0][tid] = A0; keys_sh[1][tid] = A1; keys_sh[2][tid] = A2;
    keys_sh[3][tid] = A3; keys_sh[4][tid] = A4;
    keys_sh[5][tid] = B0; keys_sh[6][tid] = B1; keys_sh[7][tid] = B2;
    keys_sh[8][tid] = B3; keys_sh[9][tid] = B4;
    keys_sh[10][tid] = C0; keys_sh[11][tid] = C1; keys_sh[12][tid] = C2;
    keys_sh[13][tid] = C3; keys_sh[14][tid] = C4;
    keys_sh[15][tid] = D0; keys_sh[16][tid] = D1; keys_sh[17][tid] = D2;
    keys_sh[18][tid] = D3; keys_sh[19][tid] = D4;
    __syncthreads();

    // ---- merge + phase C: wave w owns query slot w ----
    const float* f = points2 + (size_t)b * S;  // D = 1
    if (wid_u == 0) {
        MERGE3(0, A0, A1, A2, A3, A4, lane + 64, lane + 128, lane + 192);
        PHASE_C(nx_0, ny_0, nz_0, c_0, x_0, y_0, z_0, ss_0,
                A0, A1, A2, A3, A4, n_0);
    } else if (wid_u == 1) {
        MERGE3(5, B0, B1, B2, B3, B4, lane, lane + 128, lane + 192);
        PHASE_C(nx_1, ny_1, nz_1, c_1, x_1, y_1, z_1, ss_1,
                B0, B1, B2, B3, B4, n_1);
    } else if (wid_u == 2) {
        MERGE3(10, C0, C1, C2, C3, C4, lane, lane + 64, lane + 192);
        PHASE_C(nx_2, ny_2, nz_2, c_2, x_2, y_2, z_2, ss_2,
                C0, C1, C2, C3, C4, n_2);
    } else {
        MERGE3(15, D0, D1, D2, D3, D4, lane, lane + 64, lane + 128);
        PHASE_C(nx_3, ny_3, nz_3, c_3, x_3, y_3, z_3, ss_3,
                D0, D1, D2, D3, D4, n_3);
    }
}

extern "C" void kernel_launch(void* const* d_in, const int* in_sizes, int n_in,
                              void* d_out, int out_size, void* d_ws, size_t ws_size,
                              hipStream_t stream) {
    const float* xyz1 = (const float*)d_in[0];
    const float* xyz2 = (const float*)d_in[1];
    const float* points2 = (const float*)d_in[2];
    float* out = (float*)d_out;
    float4* ws = (float4*)d_ws;  // B*S*16 = 32 KB

    prep_kernel<<<(B * S + 255) / 256, 256, 0, stream>>>(xyz2, ws);
    // 1024 blocks x 256 threads: block covers 256 queries (Q=4 per lane),
    // candidates split 4 ways across the block's waves
    knn3_kernel<<<(B * N) / 256, 256, 0, stream>>>(xyz1, points2, ws, out);
}

// Round 17
// 32.741 us; speedup vs baseline: 1.2239x; 1.0642x over previous
//
#include <hip/hip_runtime.h>
#include <stdint.h>

// AeTransformer_44839458570443: 3-NN inverse-distance interpolation + (tanh+1)/2.
// xyz1: [B,3,N] fp32, xyz2: [B,3,S] fp32, points2: [B,1,S] fp32 -> out [B,N] fp32.
//
// Selection bit-matches the reference fp32 expanded distance
//   d = (-2*((x*x'+y*y')+z*z') + ||q||^2) + ||p||^2   (fp32, no FMA)
// ordered by (d, index).
//
// Round 17 = Round 16 + packed-fp32 phase A. Phase A is VALU-ISSUE-bound;
// v_pk_fma_f32 halves the FMA instruction count (24 -> 12 per group-query).
// Prep emits TWO layouts per batch: pair-SoA ({x0,x1},{y0,y1},{z0,z1},{w0,w1}
// per candidate pair; feeds pk ops with zero shuffling) and AoS (phase C /
// refine, bit-identical to R16). Pack = 1 v_and_or_b32 (mask in VGPR, gid is
// the single SGPR operand). pk-fma is IEEE fma per half -> proxy values and
// all selection decisions identical to R16.
// PHASE A (proxy): Q=4 x split-4; per group of 8, pk distances + min tree ->
//   group min; 5 best (group-min | gid) keys/slot. Lemma: at most 3 groups
//   can have min <= d3; 5 kept for margin.
// MERGE: wave w owns query-slot w; INS5-merges 3 partners' lists via LDS.
// PHASE C (LDS AoS gathers; R16-proven): proxy rescan of 40 survivors,
//   9-bit 6-slot screen, exact replicated ref_d on 6, (d,idx) sort,
//   replicated fp32 weight chain (proven R2-R16).
static constexpr int B = 4;
static constexpr int N = 65536;
static constexpr int S = 512;

typedef float float2v __attribute__((ext_vector_type(2)));

// ws per batch: 4096 floats. [0..2047] pair-SoA: pair pp -> 8 floats
// {x_e,x_o, y_e,y_o, z_e,z_o, w_e,w_o}; [2048..4095] AoS float4 {x,y,z,w}.
__global__ __launch_bounds__(256) void prep_kernel(const float* __restrict__ xyz2,
                                                   float* __restrict__ wsf) {
    int t = blockIdx.x * 256 + threadIdx.x;
    if (t >= B * S) return;
    int b = t >> 9, s = t & 511;
    const float* p = xyz2 + (size_t)b * 3 * S;
    float x = p[s], y = p[s + S], z = p[s + 2 * S];
    float c = __fadd_rn(__fadd_rn(__fmul_rn(x, x), __fmul_rn(y, y)), __fmul_rn(z, z));
    float* base = wsf + (size_t)b * 4096;
    int pp = s >> 1, h = s & 1;
    base[pp * 8 + 0 + h] = x;
    base[pp * 8 + 2 + h] = y;
    base[pp * 8 + 4 + h] = z;
    base[pp * 8 + 6 + h] = c;
    ((float4*)(base + 2048))[s] = make_float4(x, y, z, c);
}

// Reference-replicated fp32 distance (numpy order, no contraction)
__device__ __forceinline__ float ref_d(float x1, float y1, float z1, float ssrc, float4 p) {
    float dot = __fadd_rn(__fadd_rn(__fmul_rn(x1, p.x), __fmul_rn(y1, p.y)),
                          __fmul_rn(z1, p.z));
    float t = __fmul_rn(dot, -2.0f);
    return __fadd_rn(__fadd_rn(t, ssrc), p.w);
}

#define CAS(da_, ia_, db_, ib_)                                     \
    {                                                               \
        bool sw_ = (db_ < da_) || ((db_ == da_) && (ib_ < ia_));    \
        float tda_ = sw_ ? db_ : da_;                               \
        int tia_ = sw_ ? ib_ : ia_;                                 \
        db_ = sw_ ? da_ : db_;                                      \
        ib_ = sw_ ? ia_ : ib_;                                      \
        da_ = tda_;                                                 \
        ia_ = tia_;                                                 \
    }

// sorted insert into ascending 5-list (named slots)
#define INS5L(A0, A1, A2, A3, A4, k)                                \
    {                                                               \
        float t4 = __builtin_amdgcn_fmed3f(A3, (k), A4);            \
        float t3 = __builtin_amdgcn_fmed3f(A2, (k), A3);            \
        float t2 = __builtin_amdgcn_fmed3f(A1, (k), A2);            \
        float t1 = __builtin_amdgcn_fmed3f(A0, (k), A1);            \
        A0 = fminf(A0, (k));                                        \
        A1 = t1; A2 = t2; A3 = t3; A4 = t4;                         \
    }

#define INS6(k)                                                     \
    {                                                               \
        float t5 = __builtin_amdgcn_fmed3f(m4, (k), m5);            \
        float t4 = __builtin_amdgcn_fmed3f(m3, (k), m4);            \
        float t3 = __builtin_amdgcn_fmed3f(m2, (k), m3);            \
        float t2 = __builtin_amdgcn_fmed3f(m1, (k), m2);            \
        float t1 = __builtin_amdgcn_fmed3f(m0, (k), m1);            \
        m0 = fminf(m0, (k));                                        \
        m1 = t1; m2 = t2; m3 = t3; m4 = t4; m5 = t5;                \
    }

// Packed phase-A body for one query slot; xs/ys/zs/ww are float2v[4] pairs
#define PK_PROC(NXP, NYP, NZP, CC, A0, A1, A2, A3, A4, gid)                   \
    {                                                                         \
        float2v e0 = __builtin_elementwise_fma(                               \
            NXP, xs[0], __builtin_elementwise_fma(                            \
                            NYP, ys[0],                                       \
                            __builtin_elementwise_fma(NZP, zs[0], ww[0])));   \
        float2v e1 = __builtin_elementwise_fma(                               \
            NXP, xs[1], __builtin_elementwise_fma(                            \
                            NYP, ys[1],                                       \
                            __builtin_elementwise_fma(NZP, zs[1], ww[1])));   \
        float2v e2 = __builtin_elementwise_fma(                               \
            NXP, xs[2], __builtin_elementwise_fma(                            \
                            NYP, ys[2],                                       \
                            __builtin_elementwise_fma(NZP, zs[2], ww[2])));   \
        float2v e3 = __builtin_elementwise_fma(                               \
            NXP, xs[3], __builtin_elementwise_fma(                            \
                            NYP, ys[3],                                       \
                            __builtin_elementwise_fma(NZP, zs[3], ww[3])));   \
        float2v mA = __builtin_elementwise_min(e0, e1);                       \
        float2v mB = __builtin_elementwise_min(e2, e3);                       \
        float2v mC = __builtin_elementwise_min(mA, mB);                       \
        float gm = fminf(mC.x, mC.y);                                         \
        uint32_t kb = (__float_as_uint(gm + CC) & maskA) | (uint32_t)(gid);   \
        float gkey = __uint_as_float(kb);                                     \
        INS5L(A0, A1, A2, A3, A4, gkey);                                      \
    }

// Merge 3 partner 5-lists (rows R..R+4, partner tids P0,P1,P2) into A-list
#define MERGE3(R, A0, A1, A2, A3, A4, P0, P1, P2)                             \
    {                                                                         \
        _Pragma("unroll") for (int j = 0; j < 5; ++j) {                       \
            float k0 = keys_sh[(R) + j][P0];                                  \
            float k1 = keys_sh[(R) + j][P1];                                  \
            float k2 = keys_sh[(R) + j][P2];                                  \
            INS5L(A0, A1, A2, A3, A4, k0);                                    \
            INS5L(A0, A1, A2, A3, A4, k1);                                    \
            INS5L(A0, A1, A2, A3, A4, k2);                                    \
        }                                                                     \
    }

// Phase C + refine + epilogue for one query — all gathers from LDS AoS tile
#define PHASE_C(NX, NY, NZ, CC, X1, Y1, Z1, SS, K0, K1, K2, K3, K4, NOUT)     \
    {                                                                         \
        float m0 = 3.0e38f, m1 = 3.0e38f, m2 = 3.0e38f,                       \
              m3 = 3.0e38f, m4 = 3.0e38f, m5 = 3.0e38f;                       \
        float gkeys[5] = {K0, K1, K2, K3, K4};                                \
        _Pragma("unroll") for (int t = 0; t < 5; ++t) {                       \
            int gbase = (int)(__float_as_uint(gkeys[t]) & 63u) << 3;          \
            _Pragma("unroll") for (int j = 0; j < 8; ++j) {                   \
                float4 p = tileA[gbase + j]; /* divergent LDS gather */       \
                float e2 = fmaf(NX, p.x,                                      \
                                fmaf(NY, p.y, fmaf(NZ, p.z, p.w + CC)));      \
                float k = __uint_as_float((__float_as_uint(e2) & 0xFFFFFE00u) \
                                          | (uint32_t)(gbase + j));           \
                INS6(k);                                                      \
            }                                                                 \
        }                                                                     \
        int gi[6];                                                            \
        float dd[6];                                                          \
        gi[0] = (int)(__float_as_uint(m0) & 511u);                            \
        gi[1] = (int)(__float_as_uint(m1) & 511u);                            \
        gi[2] = (int)(__float_as_uint(m2) & 511u);                            \
        gi[3] = (int)(__float_as_uint(m3) & 511u);                            \
        gi[4] = (int)(__float_as_uint(m4) & 511u);                            \
        gi[5] = (int)(__float_as_uint(m5) & 511u);                            \
        _Pragma("unroll") for (int j = 0; j < 6; ++j)                         \
            dd[j] = ref_d(X1, Y1, Z1, SS, tileA[gi[j]]);                      \
        _Pragma("unroll") for (int pp = 0; pp < 3; ++pp)                      \
            _Pragma("unroll") for (int i = 4; i >= pp; --i)                   \
                CAS(dd[i], gi[i], dd[i + 1], gi[i + 1]);                      \
        const float EPS32 = 1e-8f;                                            \
        float r0 = __fdiv_rn(1.0f, __fadd_rn(dd[0], EPS32));                  \
        float r1 = __fdiv_rn(1.0f, __fadd_rn(dd[1], EPS32));                  \
        float r2 = __fdiv_rn(1.0f, __fadd_rn(dd[2], EPS32));                  \
        float rs = __fadd_rn(__fadd_rn(r0, r1), r2);                          \
        float w0 = __fdiv_rn(r0, rs);                                         \
        float w1 = __fdiv_rn(r1, rs);                                         \
        float w2 = __fdiv_rn(r2, rs);                                         \
        float interp = __fadd_rn(__fadd_rn(__fmul_rn(f[gi[0]], w0),           \
                                           __fmul_rn(f[gi[1]], w1)),          \
                                 __fmul_rn(f[gi[2]], w2));                    \
        float th = tanhf(interp);                                             \
        out[((size_t)b << 16) | (uint32_t)(NOUT)] =                           \
            __fmul_rn(__fadd_rn(th, 1.0f), 0.5f);                             \
    }

__global__ __launch_bounds__(256, 4) void knn3_kernel(const float* __restrict__ xyz1,
                                                      const float* __restrict__ points2,
                                                      const float* __restrict__ wsf,
                                                      float* __restrict__ out) {
    __shared__ float4 tile2[S];         // 8 KB pair-SoA (phase A pk feeds)
    __shared__ float4 tileA[S];         // 8 KB AoS (phase C / refine)
    __shared__ float keys_sh[20][256];  // 20 KB per-slot key exchange
    const int tid = threadIdx.x;
    const int lane = tid & 63;
    const int wid_u = __builtin_amdgcn_readfirstlane(tid >> 6);  // wave 0-3
    const int b = blockIdx.x >> 8;      // 256 blocks per batch
    const int base = (blockIdx.x & 255) << 8;  // block covers 256 queries

    const float* wsb = wsf + (size_t)b * 4096;
    const float4* __restrict__ wsP4 = (const float4*)wsb;          // pair-SoA
    const float4* __restrict__ wsA4 = (const float4*)(wsb + 2048); // AoS
    tile2[tid] = wsP4[tid];
    tile2[tid + 256] = wsP4[tid + 256];
    tileA[tid] = wsA4[tid];
    tileA[tid + 256] = wsA4[tid + 256];
    __syncthreads();

    // 4 query slots per lane: n_s = base + s*64 + lane (coalesced loads)
    const int n_0 = base + lane, n_1 = n_0 + 64, n_2 = n_0 + 128, n_3 = n_0 + 192;
    const float* q = xyz1 + (size_t)b * 3 * N;
    float x_0 = q[n_0], y_0 = q[n_0 + N], z_0 = q[n_0 + 2 * N];
    float x_1 = q[n_1], y_1 = q[n_1 + N], z_1 = q[n_1 + 2 * N];
    float x_2 = q[n_2], y_2 = q[n_2 + N], z_2 = q[n_2 + 2 * N];
    float x_3 = q[n_3], y_3 = q[n_3 + N], z_3 = q[n_3 + 2 * N];
#define MKC(s)                                                                     \
    float ss_##s = __fadd_rn(__fadd_rn(__fmul_rn(x_##s, x_##s),                    \
                                       __fmul_rn(y_##s, y_##s)),                   \
                             __fmul_rn(z_##s, z_##s));                             \
    float c_##s = ss_##s + 0.25f;                                                  \
    float nx_##s = -2.0f * x_##s, ny_##s = -2.0f * y_##s, nz_##s = -2.0f * z_##s;  \
    float2v nxp_##s = {nx_##s, nx_##s};                                            \
    float2v nyp_##s = {ny_##s, ny_##s};                                            \
    float2v nzp_##s = {nz_##s, nz_##s};
    MKC(0) MKC(1) MKC(2) MKC(3)
#undef MKC

    uint32_t maskA = 0xFFFFFFC0u;     // VGPR mask -> single v_and_or_b32
    asm volatile("" : "+v"(maskA));

    // ---- Phase A: scan own 16 groups (pk distances); 5 best per slot ----
    float A0 = 3.0e38f, A1 = 3.0e38f, A2 = 3.0e38f, A3 = 3.0e38f, A4 = 3.0e38f;
    float B0 = 3.0e38f, B1 = 3.0e38f, B2 = 3.0e38f, B3 = 3.0e38f, B4 = 3.0e38f;
    float C0 = 3.0e38f, C1 = 3.0e38f, C2 = 3.0e38f, C3 = 3.0e38f, C4 = 3.0e38f;
    float D0 = 3.0e38f, D1 = 3.0e38f, D2 = 3.0e38f, D3 = 3.0e38f, D4 = 3.0e38f;
    const int gid0 = wid_u << 4;
#pragma unroll 2
    for (int g = 0; g < 16; ++g) {
        const int gid = gid0 + g;
        // group = 4 candidate pairs = 8 float4 (pair-SoA), broadcast b128
        float2v xs[4], ys[4], zs[4], ww[4];
#pragma unroll
        for (int k = 0; k < 4; ++k) {
            float4 pa = tile2[gid * 8 + 2 * k];      // {x_e,x_o,y_e,y_o}
            float4 pb = tile2[gid * 8 + 2 * k + 1];  // {z_e,z_o,w_e,w_o}
            xs[k] = (float2v){pa.x, pa.y};
            ys[k] = (float2v){pa.z, pa.w};
            zs[k] = (float2v){pb.x, pb.y};
            ww[k] = (float2v){pb.z, pb.w};
        }
        PK_PROC(nxp_0, nyp_0, nzp_0, c_0, A0, A1, A2, A3, A4, gid);
        PK_PROC(nxp_1, nyp_1, nzp_1, c_1, B0, B1, B2, B3, B4, gid);
        PK_PROC(nxp_2, nyp_2, nzp_2, c_2, C0, C1, C2, C3, C4, gid);
        PK_PROC(nxp_3, nyp_3, nzp_3, c_3, D0, D1, D2, D3, D4, gid);
    }

    // ---- publish all 20 keys ----
    keys_sh[0][tid] = A0; keys_sh[1][tid] = A1; keys_sh[2][tid] = A2;
    keys_sh[3][tid] = A3; keys_sh[4][tid] = A4;
    keys_sh[5][tid] = B0; keys_sh[6][tid] = B1; keys_sh[7][tid] = B2;
    keys_sh[8][tid] = B3; keys_sh[9][tid] = B4;
    keys_sh[10][tid] = C0; keys_sh[11][tid] = C1; keys_sh[12][tid] = C2;
    keys_sh[13][tid] = C3; keys_sh[14][tid] = C4;
    keys_sh[15][tid] = D0; keys_sh[16][tid] = D1; keys_sh[17][tid] = D2;
    keys_sh[18][tid] = D3; keys_sh[19][tid] = D4;
    __syncthreads();

    // ---- merge + phase C: wave w owns query slot w ----
    const float* f = points2 + (size_t)b * S;  // D = 1
    if (wid_u == 0) {
        MERGE3(0, A0, A1, A2, A3, A4, lane + 64, lane + 128, lane + 192);
        PHASE_C(nx_0, ny_0, nz_0, c_0, x_0, y_0, z_0, ss_0,
                A0, A1, A2, A3, A4, n_0);
    } else if (wid_u == 1) {
        MERGE3(5, B0, B1, B2, B3, B4, lane, lane + 128, lane + 192);
        PHASE_C(nx_1, ny_1, nz_1, c_1, x_1, y_1, z_1, ss_1,
                B0, B1, B2, B3, B4, n_1);
    } else if (wid_u == 2) {
        MERGE3(10, C0, C1, C2, C3, C4, lane, lane + 64, lane + 192);
        PHASE_C(nx_2, ny_2, nz_2, c_2, x_2, y_2, z_2, ss_2,
                C0, C1, C2, C3, C4, n_2);
    } else {
        MERGE3(15, D0, D1, D2, D3, D4, lane, lane + 64, lane + 128);
        PHASE_C(nx_3, ny_3, nz_3, c_3, x_3, y_3, z_3, ss_3,
                D0, D1, D2, D3, D4, n_3);
    }
}

extern "C" void kernel_launch(void* const* d_in, const int* in_sizes, int n_in,
                              void* d_out, int out_size, void* d_ws, size_t ws_size,
                              hipStream_t stream) {
    const float* xyz1 = (const float*)d_in[0];
    const float* xyz2 = (const float*)d_in[1];
    const float* points2 = (const float*)d_in[2];
    float* out = (float*)d_out;
    float* wsf = (float*)d_ws;  // 64 KB: pair-SoA + AoS tables per batch

    prep_kernel<<<(B * S + 255) / 256, 256, 0, stream>>>(xyz2, wsf);
    // 1024 blocks x 256 threads: block covers 256 queries (Q=4 per lane),
    // candidates split 4 ways across the block's waves
    knn3_kernel<<<(B * N) / 256, 256, 0, stream>>>(xyz1, points2, wsf, out);
}